// Round 2
// baseline (1015.359 us; speedup 1.0000x reference)
//
#include <hip/hip_runtime.h>

// ---------------- problem constants ----------------
#define BATCH   32768
#define NLINE   411
#define NTILES  14            // 5 quad + 7 Ibr + 2 stat n-tiles of 128
#define RTILES  256           // 32768 / 128

typedef __attribute__((ext_vector_type(8))) short  short8;
typedef __attribute__((ext_vector_type(4))) float  f32x4;

// ---------------- workspace layout (bytes) ----------------
#define WS_SCALAR   0
#define WS_KROWS    64                       // 32768 f32
#define WS_MAPL     131136                   // 600 f32
#define WS_MAPG     133536                   // 138 f32
#define WS_ATMP     134144                   // 822*600 f32 = 1972800 B
#define WS_BMF      2106944                  // 14*10*1024*16 B = 2293760
#define WS_ZERO_BYTES 131136                 // scalar + kkt_rows only

__device__ __forceinline__ unsigned short f2bf(float f) {
    unsigned int u = __float_as_uint(f);
    unsigned int r = (u + 0x7FFFu + ((u >> 16) & 1u)) >> 16;
    return (unsigned short)r;
}

#if defined(__has_builtin)
#  if __has_builtin(__builtin_amdgcn_cvt_pk_bf16_f32)
#    define HAVE_PK_BF16 1
#  endif
#endif

__device__ __forceinline__ unsigned int pk2bf(float a, float b) {
#ifdef HAVE_PK_BF16
    typedef __bf16 bf16x2 __attribute__((ext_vector_type(2)));
    bf16x2 r = __builtin_amdgcn_cvt_pk_bf16_f32(a, b);
    return __builtin_bit_cast(unsigned int, r);
#else
    return (unsigned int)f2bf(a) | ((unsigned int)f2bf(b) << 16);
#endif
}

// ---------------- prep: masked column sums for mism ----------------
__global__ void prep_colsums(const float* __restrict__ MapL, const float* __restrict__ Mapg,
                             float* __restrict__ mapL_s, float* __restrict__ mapg_s) {
    int w = threadIdx.x >> 6, lane = threadIdx.x & 63;
    int row = blockIdx.x * 4 + w;
    const float* src;
    float* dst;
    if (row < 600)      { src = MapL + (size_t)row * 600; dst = mapL_s + row; }
    else if (row < 738) { src = Mapg + (size_t)(row - 600) * 600; dst = mapg_s + (row - 600); }
    else return;
    float s = 0.f;
    for (int j = lane; j < 600; j += 64)
        if (j != 299 && j != 599) s += src[j];
    for (int m = 32; m >= 1; m >>= 1) s += __shfl_xor(s, m);
    if (lane == 0) *dst = s;
}

// ---------------- prep: A = Ybr @ IM  (822x600), full-K per block, no atomics ----------------
__global__ __launch_bounds__(256) void prep_A(const float* __restrict__ Ybr,
                                              const float* __restrict__ IM,
                                              float* __restrict__ Atmp) {
    int t2 = blockIdx.x;
    int bc = t2 % 10, br = t2 / 10;          // 13 x 10 tiles of 64x64
    int r0 = br * 64, c0 = bc * 64;

    __shared__ float Yt[64][33];
    __shared__ float Xt[32][65];
    int t = threadIdx.x;
    int tx = t & 15, ty = t >> 4;
    float c[4][4] = {};

    for (int kk = 0; kk < 822; kk += 32) {
        __syncthreads();
        for (int e = t; e < 2048; e += 256) {
            int yr = e >> 5, yk = e & 31;
            int gr = r0 + yr, gk = kk + yk;
            Yt[yr][yk] = (gr < 822 && gk < 822) ? Ybr[(size_t)gr * 822 + gk] : 0.f;
        }
        for (int e = t; e < 2048; e += 256) {
            int xk = e >> 6, xc = e & 63;
            int gk = kk + xk, gc = c0 + xc;
            Xt[xk][xc] = (gk < 822 && gc < 600) ? IM[(size_t)gk * 600 + gc] : 0.f;
        }
        __syncthreads();
        for (int k2 = 0; k2 < 32; ++k2) {
            float a[4], b[4];
#pragma unroll
            for (int ii = 0; ii < 4; ++ii) a[ii] = Yt[ty * 4 + ii][k2];
#pragma unroll
            for (int jj = 0; jj < 4; ++jj) b[jj] = Xt[k2][tx * 4 + jj];
#pragma unroll
            for (int ii = 0; ii < 4; ++ii)
#pragma unroll
                for (int jj = 0; jj < 4; ++jj) c[ii][jj] += a[ii] * b[jj];
        }
    }
#pragma unroll
    for (int ii = 0; ii < 4; ++ii)
#pragma unroll
        for (int jj = 0; jj < 4; ++jj) {
            int gr = r0 + ty * 4 + ii, gc = c0 + tx * 4 + jj;
            if (gr < 822 && gc < 600) Atmp[(size_t)gr * 600 + gc] = c[ii][jj];
        }
}

// ---------------- prep: pack combined B into MFMA-fragment order per (nt,kc) ----------------
// BmF[((nt*10+kc)*1024 + S)] is a short8; S -> (rc,kb): ig=S>>7, ks=(S>>6)&1, ln=S&63,
// rc = ig*16+(ln&15), kb = ks*32+((ln>>4)<<3)
__global__ void prep_packF(const float* __restrict__ Y, const float* __restrict__ Yconj,
                           const float* __restrict__ Mapg, const float* __restrict__ Atmp,
                           unsigned short* __restrict__ BmF) {
    int nt = blockIdx.x / 10, kc = blockIdx.x % 10;
    int t = threadIdx.x;
#pragma unroll
    for (int m = 0; m < 4; ++m) {
        int S = m * 256 + t;
        int ig = S >> 7, ks = (S >> 6) & 1, ln = S & 63;
        int rc = ig * 16 + (ln & 15);
        int kb = ks * 32 + ((ln >> 4) << 3);
        int n = nt * 128 + rc;
        unsigned short out[8];
#pragma unroll
        for (int j = 0; j < 8; ++j) {
            int k = kc * 64 + kb + j;
            float v = 0.f;
            if (k < 600) {
                if (n < 600) {
                    if (n != 299 && n != 599)
                        v = Y[(size_t)n * 600 + k] + Yconj[(size_t)n * 600 + k];
                } else if (n >= 640 && n < 1536) {
                    int idx = n - 640;
                    int l = idx >> 1, h = idx & 1;
                    if (l < NLINE) v = Atmp[(size_t)(h * NLINE + l) * 600 + k];
                } else if (n >= 1536) {
                    int g = n - 1536;
                    if (g < 138) v = Mapg[(size_t)g * 600 + k];
                }
            }
            out[j] = f2bf(v);
        }
        *(short8*)(BmF + (size_t)((nt * 10 + kc) * 1024 + S) * 8) = *(short8*)out;
    }
}

// ---------------- main fused GEMM + epilogues ----------------
__global__ __launch_bounds__(256, 3) void kkt_main(
    const float* __restrict__ Volt, const float* __restrict__ PG, const float* __restrict__ PL,
    const float* __restrict__ nolp, const float* __restrict__ mu_gu, const float* __restrict__ mu_gd,
    const float* __restrict__ mu_vu, const float* __restrict__ mu_vd, const float* __restrict__ mu_iu,
    const float* __restrict__ Gmax, const float* __restrict__ Gmin, const float* __restrict__ CPg,
    const unsigned short* __restrict__ BmF, const float* __restrict__ mapL_s,
    const float* __restrict__ mapg_s, float* __restrict__ kkt_rows, float* __restrict__ scalar_acc) {

    // XCD-aware swizzle: pin a rowtile's 14 n-tile blocks to one XCD for L2 reuse of Volt rows.
    int idx = blockIdx.x;
    int xcd = idx & 7;
    int q = idx >> 3;
    int nt = q % NTILES;
    int rg = q / NTILES;
    int rt = rg * 8 + xcd;
    int b0 = rt * 128;

    int t = threadIdx.x;
    int lane = t & 63, w = t >> 6, wr = w >> 1, wc = w & 1;

    __shared__ unsigned short At[128 * 72];   // A tile linear [row][k], stride 72 (conflict-free, 16B-aligned)
    __shared__ short8 Bsm[1024];              // B tile in MFMA-fragment order
    __shared__ float  redbuf[4];

    const float* Abase = (nt < 12) ? Volt : nolp;

    f32x4 acc[4][4] = {};

    int arow = t >> 4;          // 0..15
    int c4 = (t & 15) * 4;      // 0..60

    for (int kc = 0; kc < 10; ++kc) {
        int k0 = kc * 64;
        __syncthreads();
        // B: async linear copy global->LDS (fragment order pre-packed)
        const unsigned short* bSrc = BmF + (size_t)((nt * 10 + kc) * 1024) * 8;
#pragma unroll
        for (int m = 0; m < 4; ++m) {
            int S = m * 256 + t;
            __builtin_amdgcn_global_load_lds(
                (const __attribute__((address_space(1))) unsigned int*)(bSrc + (size_t)S * 8),
                (__attribute__((address_space(3))) unsigned int*)&Bsm[S], 16, 0, 0);
        }
        // A: coalesced fp32 read (4 rows x 256B per wave-instr), pack-convert, LDS linear
        bool valid = (k0 + c4) < 600;
#pragma unroll
        for (int j = 0; j < 8; ++j) {
            int row = j * 16 + arow;
            uint2 p = make_uint2(0u, 0u);
            if (valid) {
                f32x4 x = *(const f32x4*)(Abase + (size_t)(b0 + row) * 600 + k0 + c4);
                p.x = pk2bf(x[0], x[1]);
                p.y = pk2bf(x[2], x[3]);
            }
            *(uint2*)&At[row * 72 + c4] = p;
        }
        __syncthreads();
#pragma unroll
        for (int ks = 0; ks < 2; ++ks) {
            short8 af[4], bfr[4];
#pragma unroll
            for (int ii = 0; ii < 4; ++ii)
                af[ii] = *(const short8*)&At[(wr * 64 + ii * 16 + (lane & 15)) * 72 + ks * 32 + ((lane >> 4) << 3)];
#pragma unroll
            for (int jj = 0; jj < 4; ++jj) bfr[jj] = Bsm[((wc * 4 + jj) * 2 + ks) * 64 + lane];
#pragma unroll
            for (int ii = 0; ii < 4; ++ii)
#pragma unroll
                for (int jj = 0; jj < 4; ++jj)
                    acc[ii][jj] = __builtin_amdgcn_mfma_f32_16x16x32_bf16(af[ii], bfr[jj], acc[ii][jj], 0, 0, 0);
        }
    }

    // ---- section epilogues ----
    // C/D layout (m89): col = lane&15, row = (lane>>4)*4 + reg
    if (nt < 5) {
        // quad: global scalar += sum u*v
        float qa = 0.f;
#pragma unroll
        for (int ii = 0; ii < 4; ++ii)
#pragma unroll
            for (int jj = 0; jj < 4; ++jj)
#pragma unroll
                for (int r2 = 0; r2 < 4; ++r2) {
                    int row = wr * 64 + ii * 16 + ((lane >> 4) << 2) + r2;
                    int col = nt * 128 + wc * 64 + jj * 16 + (lane & 15);
                    if (col < 600) {
                        float v = Volt[(size_t)(b0 + row) * 600 + col];
                        qa += acc[ii][jj][r2] * v;
                    }
                }
        for (int m = 32; m >= 1; m >>= 1) qa += __shfl_xor(qa, m);
        if (lane == 0) redbuf[w] = qa;
        __syncthreads();
        if (t == 0) atomicAdd(scalar_acc, redbuf[0] + redbuf[1] + redbuf[2] + redbuf[3]);
    } else if (nt < 12) {
        // Ibr: i_up = re^2 + im^2 - 1 on interleaved column pairs
        float racc[16];
#pragma unroll
        for (int s = 0; s < 16; ++s) racc[s] = 0.f;
#pragma unroll
        for (int ii = 0; ii < 4; ++ii)
#pragma unroll
            for (int jj = 0; jj < 4; ++jj)
#pragma unroll
                for (int r2 = 0; r2 < 4; ++r2) {
                    float u = acc[ii][jj][r2];
                    float up = __shfl_xor(u, 1);
                    int col = nt * 128 + wc * 64 + jj * 16 + (lane & 15);
                    int l = (col - 640) >> 1;
                    float contrib = 0.f;
                    if (l < NLINE && !(lane & 1)) {
                        int row = wr * 64 + ii * 16 + ((lane >> 4) << 2) + r2;
                        float iu = u * u + up * up - 1.0f;
                        float mu = mu_iu[(size_t)(b0 + row) * NLINE + l];
                        contrib = fmaxf(iu, 0.f) + fabsf(mu * iu) + fmaxf(-mu, 0.f);
                    }
                    racc[ii * 4 + r2] += contrib;
                }
#pragma unroll
        for (int s = 0; s < 16; ++s) {
            float v = racc[s];
            v += __shfl_xor(v, 1); v += __shfl_xor(v, 2);
            v += __shfl_xor(v, 4); v += __shfl_xor(v, 8);
            if ((lane & 15) == 0) {
                int row = wr * 64 + (s >> 2) * 16 + ((lane >> 4) << 2) + (s & 3);
                atomicAdd(kkt_rows + b0 + row, v);
            }
        }
    } else {
        // stat + gen-limit terms + P_Gens part of mism
        float racc[16];
#pragma unroll
        for (int s = 0; s < 16; ++s) racc[s] = 0.f;
#pragma unroll
        for (int ii = 0; ii < 4; ++ii)
#pragma unroll
            for (int jj = 0; jj < 4; ++jj)
#pragma unroll
                for (int r2 = 0; r2 < 4; ++r2) {
                    int col = nt * 128 + wc * 64 + jj * 16 + (lane & 15);
                    int g = col - 1536;
                    float contrib = 0.f;
                    if (g < 138) {
                        int row = wr * 64 + ii * 16 + ((lane >> 4) << 2) + r2;
                        size_t ix = (size_t)(b0 + row) * 138 + g;
                        float u = acc[ii][jj][r2];
                        float gu = mu_gu[ix], gd = mu_gd[ix], pg = PG[ix];
                        float gmx = Gmax[g], gmn = Gmin[g];
                        float cst = (g < 69) ? CPg[g] : 0.f;
                        float t1 = pg - gmx, t2 = gmn - pg;
                        float st = u + gu - gd - cst;
                        contrib = fabsf(st) + fmaxf(t1, 0.f) + fmaxf(t2, 0.f)
                                + (fabsf(gu * t1) + fabsf(gd * t2)) * (1.0f / 69.0f)
                                + fmaxf(-gu, 0.f) + fmaxf(-gd, 0.f)
                                - 32768.0f * pg * mapg_s[g];
                    }
                    racc[ii * 4 + r2] += contrib;
                }
#pragma unroll
        for (int s = 0; s < 16; ++s) {
            float v = racc[s];
            v += __shfl_xor(v, 1); v += __shfl_xor(v, 2);
            v += __shfl_xor(v, 4); v += __shfl_xor(v, 8);
            if ((lane & 15) == 0) {
                int row = wr * 64 + (s >> 2) * 16 + ((lane >> 4) << 2) + (s & 3);
                atomicAdd(kkt_rows + b0 + row, v);
            }
        }
    }

    // ---- extra per-rowtile duties, assigned to specific ntile blocks ----
    if (nt == 0) {
        // voltage-magnitude constraint terms (exact fp32)
        for (int m = 0; m < 32; ++m) {
            int b = b0 + w * 32 + m;
            float s = 0.f;
            for (int j = lane; j < 300; j += 64) {
                float vr = Volt[(size_t)b * 600 + j];
                float vi = Volt[(size_t)b * 600 + 300 + j];
                float muu = mu_vu[(size_t)b * 300 + j];
                float mud = mu_vd[(size_t)b * 300 + j];
                float sq = vr * vr, si = vi * vi;
                float vu = sq + si - 1.1236f;        // VMAX^2
                float vd = 0.8836f - sq + si;        // VMIN^2 - Vre^2 + Vim^2 (per reference!)
                s += fmaxf(vu, 0.f) + fmaxf(vd, 0.f) + fabsf(muu * vu) + fabsf(mud * vd)
                   + fmaxf(-muu, 0.f) + fmaxf(-mud, 0.f);
            }
            for (int mm = 32; mm >= 1; mm >>= 1) s += __shfl_xor(s, mm);
            if (lane == 0) atomicAdd(kkt_rows + b, s);
        }
    } else if (nt == 1) {
        // B * (P_Loads . mapL_s)
        for (int m = 0; m < 32; ++m) {
            int b = b0 + w * 32 + m;
            float s = 0.f;
            for (int j = lane; j < 600; j += 64)
                s += PL[(size_t)b * 600 + j] * mapL_s[j];
            for (int mm = 32; mm >= 1; mm >>= 1) s += __shfl_xor(s, mm);
            if (lane == 0) atomicAdd(kkt_rows + b, 32768.0f * s);
        }
    } else if (nt == 2) {
        // global scalar: sum_b |Volt[b, 300]|
        float v = (t < 128) ? fabsf(Volt[(size_t)(b0 + t) * 600 + 300]) : 0.f;
        for (int mm = 32; mm >= 1; mm >>= 1) v += __shfl_xor(v, mm);
        __syncthreads();
        if (lane == 0) redbuf[w] = v;
        __syncthreads();
        if (t == 0) atomicAdd(scalar_acc, redbuf[0] + redbuf[1] + redbuf[2] + redbuf[3]);
    }
}

// ---------------- finalize ----------------
__global__ void finalize_k(const float* __restrict__ kkt_rows, const float* __restrict__ scalar_acc,
                           float* __restrict__ out) {
    int i = blockIdx.x * 256 + threadIdx.x;
    out[i] = kkt_rows[i] + scalar_acc[0];
}

extern "C" void kernel_launch(void* const* d_in, const int* in_sizes, int n_in,
                              void* d_out, int out_size, void* d_ws, size_t ws_size,
                              hipStream_t stream) {
    const float* Volt  = (const float*)d_in[0];
    const float* PG    = (const float*)d_in[1];
    const float* PL    = (const float*)d_in[2];
    const float* nolp  = (const float*)d_in[3];
    const float* mu_gu = (const float*)d_in[4];
    const float* mu_gd = (const float*)d_in[5];
    const float* mu_vu = (const float*)d_in[6];
    const float* mu_vd = (const float*)d_in[7];
    const float* mu_iu = (const float*)d_in[8];
    const float* Y     = (const float*)d_in[9];
    const float* Yconj = (const float*)d_in[10];
    const float* Ybr   = (const float*)d_in[11];
    const float* IM    = (const float*)d_in[12];
    const float* Mapg  = (const float*)d_in[13];
    const float* MapL  = (const float*)d_in[14];
    const float* Gmax  = (const float*)d_in[15];
    const float* Gmin  = (const float*)d_in[16];
    const float* CPg   = (const float*)d_in[17];

    char* ws = (char*)d_ws;
    float* scalar_acc       = (float*)(ws + WS_SCALAR);
    float* kkt_rows         = (float*)(ws + WS_KROWS);
    float* mapLs            = (float*)(ws + WS_MAPL);
    float* mapgs            = (float*)(ws + WS_MAPG);
    float* Atmp             = (float*)(ws + WS_ATMP);
    unsigned short* BmF     = (unsigned short*)(ws + WS_BMF);

    hipMemsetAsync(d_ws, 0, WS_ZERO_BYTES, stream);
    prep_colsums<<<185, 256, 0, stream>>>(MapL, Mapg, mapLs, mapgs);
    prep_A<<<130, 256, 0, stream>>>(Ybr, IM, Atmp);
    prep_packF<<<140, 256, 0, stream>>>(Y, Yconj, Mapg, Atmp, BmF);
    kkt_main<<<RTILES * NTILES, 256, 0, stream>>>(Volt, PG, PL, nolp, mu_gu, mu_gd,
                                                  mu_vu, mu_vd, mu_iu, Gmax, Gmin, CPg,
                                                  BmF, mapLs, mapgs, kkt_rows, scalar_acc);
    finalize_k<<<BATCH / 256, 256, 0, stream>>>(kkt_rows, scalar_acc, (float*)d_out);
}

// Round 3
// 789.834 us; speedup vs baseline: 1.2855x; 1.2855x over previous
//
#include <hip/hip_runtime.h>

// ---------------- problem constants ----------------
#define BATCH   32768
#define NLINE   411
#define NTILES  14            // 5 quad + 7 Ibr + 2 stat n-tiles of 128
#define RTILES  256           // 32768 / 128

typedef __attribute__((ext_vector_type(8))) short  short8;
typedef __attribute__((ext_vector_type(4))) float  f32x4;

// ---------------- workspace layout (bytes) ----------------
#define WS_SCALAR   0
#define WS_KROWS    64                       // 32768 f32
#define WS_MAPL     131136                   // 600 f32
#define WS_MAPG     133536                   // 138 f32 (pad to 134144)
#define WS_ATMP     134144                   // 822*600 f32 = 1972800
#define WS_BMF      2106944                  // 14*10*1024*16 = 2293760
#define WS_VBF      4400704                  // 32768*640 bf16 = 41943040
#define WS_NEED_FAST (4400704 + 41943040)    // 46343744
#define WS_ZERO_BYTES 2106944                // scalar..Atmp

__device__ __forceinline__ unsigned short f2bf(float f) {
    unsigned int u = __float_as_uint(f);
    unsigned int r = (u + 0x7FFFu + ((u >> 16) & 1u)) >> 16;
    return (unsigned short)r;
}

#if defined(__has_builtin)
#  if __has_builtin(__builtin_amdgcn_cvt_pk_bf16_f32)
#    define HAVE_PK_BF16 1
#  endif
#endif

__device__ __forceinline__ unsigned int pk2bf(float a, float b) {
#ifdef HAVE_PK_BF16
    typedef __bf16 bf16x2 __attribute__((ext_vector_type(2)));
    bf16x2 r = __builtin_amdgcn_cvt_pk_bf16_f32(a, b);
    return __builtin_bit_cast(unsigned int, r);
#else
    return (unsigned int)f2bf(a) | ((unsigned int)f2bf(b) << 16);
#endif
}

// ---------------- prep: masked column sums for mism ----------------
__global__ void prep_colsums(const float* __restrict__ MapL, const float* __restrict__ Mapg,
                             float* __restrict__ mapL_s, float* __restrict__ mapg_s) {
    int w = threadIdx.x >> 6, lane = threadIdx.x & 63;
    int row = blockIdx.x * 4 + w;
    const float* src;
    float* dst;
    if (row < 600)      { src = MapL + (size_t)row * 600; dst = mapL_s + row; }
    else if (row < 738) { src = Mapg + (size_t)(row - 600) * 600; dst = mapg_s + (row - 600); }
    else return;
    float s = 0.f;
    for (int j = lane; j < 600; j += 64)
        if (j != 299 && j != 599) s += src[j];
    for (int m = 32; m >= 1; m >>= 1) s += __shfl_xor(s, m);
    if (lane == 0) *dst = s;
}

// ---------------- prep: A = Ybr @ IM  (822x600), split-K fp32 with atomics ----------------
__global__ __launch_bounds__(256) void prep_A(const float* __restrict__ Ybr,
                                              const float* __restrict__ IM,
                                              float* __restrict__ Atmp) {
    int bid = blockIdx.x;
    int ks = bid & 3;
    int t2 = bid >> 2;
    int bc = t2 % 10, br = t2 / 10;          // 13 x 10 tiles of 64x64
    int r0 = br * 64, c0 = bc * 64;
    int kb = ks * 206;
    int ke = (kb + 206 < 822) ? kb + 206 : 822;

    __shared__ float Yt[64][33];
    __shared__ float Xt[32][65];
    int t = threadIdx.x;
    int tx = t & 15, ty = t >> 4;
    float c[4][4] = {};

    for (int kk = kb; kk < ke; kk += 32) {
        __syncthreads();
        for (int e = t; e < 2048; e += 256) {
            int yr = e >> 5, yk = e & 31;
            int gr = r0 + yr, gk = kk + yk;
            Yt[yr][yk] = (gr < 822 && gk < ke) ? Ybr[(size_t)gr * 822 + gk] : 0.f;
        }
        for (int e = t; e < 2048; e += 256) {
            int xk = e >> 6, xc = e & 63;
            int gk = kk + xk, gc = c0 + xc;
            Xt[xk][xc] = (gk < ke && gc < 600) ? IM[(size_t)gk * 600 + gc] : 0.f;
        }
        __syncthreads();
        for (int k2 = 0; k2 < 32; ++k2) {
            float a[4], b[4];
#pragma unroll
            for (int ii = 0; ii < 4; ++ii) a[ii] = Yt[ty * 4 + ii][k2];
#pragma unroll
            for (int jj = 0; jj < 4; ++jj) b[jj] = Xt[k2][tx * 4 + jj];
#pragma unroll
            for (int ii = 0; ii < 4; ++ii)
#pragma unroll
                for (int jj = 0; jj < 4; ++jj) c[ii][jj] += a[ii] * b[jj];
        }
    }
#pragma unroll
    for (int ii = 0; ii < 4; ++ii)
#pragma unroll
        for (int jj = 0; jj < 4; ++jj) {
            int gr = r0 + ty * 4 + ii, gc = c0 + tx * 4 + jj;
            if (gr < 822 && gc < 600) atomicAdd(Atmp + (size_t)gr * 600 + gc, c[ii][jj]);
        }
}

// ---------------- prep: pack combined B into MFMA-fragment order per (nt,kc) ----------------
// slot S -> (rc,kb): ig=S>>7, ks=(S>>6)&1, ln=S&63, rc = ig*16+(ln&15), kb = ks*32+((ln>>4)<<3)
__global__ void prep_packF(const float* __restrict__ Y, const float* __restrict__ Yconj,
                           const float* __restrict__ Mapg, const float* __restrict__ Atmp,
                           unsigned short* __restrict__ BmF) {
    int ntkc = blockIdx.x >> 2;
    int nt = ntkc / 10, kc = ntkc % 10;
    int S = (blockIdx.x & 3) * 256 + threadIdx.x;
    int ig = S >> 7, ks = (S >> 6) & 1, ln = S & 63;
    int rc = ig * 16 + (ln & 15);
    int kb = ks * 32 + ((ln >> 4) << 3);
    int n = nt * 128 + rc;
    unsigned short out[8];
#pragma unroll
    for (int j = 0; j < 8; ++j) {
        int k = kc * 64 + kb + j;
        float v = 0.f;
        if (k < 600) {
            if (n < 600) {
                if (n != 299 && n != 599)
                    v = Y[(size_t)n * 600 + k] + Yconj[(size_t)n * 600 + k];
            } else if (n >= 640 && n < 1536) {
                int idx = n - 640;
                int l = idx >> 1, h = idx & 1;
                if (l < NLINE) v = Atmp[(size_t)(h * NLINE + l) * 600 + k];
            } else if (n >= 1536) {
                int g = n - 1536;
                if (g < 138) v = Mapg[(size_t)g * 600 + k];
            }
        }
        out[j] = f2bf(v);
    }
    *(short8*)(BmF + (size_t)(ntkc * 1024 + S) * 8) = *(short8*)out;
}

// ---------------- prep: duties + (optional) Volt -> padded bf16 ----------------
// One wave per batch row, 4 rows per block, grid 8192.
__global__ __launch_bounds__(256) void prep_duties_conv(
    const float* __restrict__ Volt, const float* __restrict__ PL,
    const float* __restrict__ mu_vu, const float* __restrict__ mu_vd,
    const float* __restrict__ mapL_s, unsigned short* __restrict__ Vbf,
    float* __restrict__ kkt_rows, float* __restrict__ scalar_acc, int doConv) {
    __shared__ float mls[600];
    __shared__ float sred[4];
    int t = threadIdx.x;
    for (int j = t; j < 600; j += 256) mls[j] = mapL_s[j];
    __syncthreads();
    int w = t >> 6, lane = t & 63;
    int b = blockIdx.x * 4 + w;

    if (doConv) {
        for (int c = lane * 4; c < 600; c += 256) {
            f32x4 x = *(const f32x4*)(Volt + (size_t)b * 600 + c);
            uint2 p;
            p.x = pk2bf(x[0], x[1]);
            p.y = pk2bf(x[2], x[3]);
            *(uint2*)(Vbf + (size_t)b * 640 + c) = p;
        }
        if (lane < 10) {
            uint2 z = make_uint2(0u, 0u);
            *(uint2*)(Vbf + (size_t)b * 640 + 600 + lane * 4) = z;
        }
    }
    // v_up / v_dn duty
    float s = 0.f;
    for (int j = lane; j < 300; j += 64) {
        float vr = Volt[(size_t)b * 600 + j];
        float vi = Volt[(size_t)b * 600 + 300 + j];
        float muu = mu_vu[(size_t)b * 300 + j];
        float mud = mu_vd[(size_t)b * 300 + j];
        float sq = vr * vr, si = vi * vi;
        float vu = sq + si - 1.1236f;
        float vd = 0.8836f - sq + si;
        s += fmaxf(vu, 0.f) + fmaxf(vd, 0.f) + fabsf(muu * vu) + fabsf(mud * vd)
           + fmaxf(-muu, 0.f) + fmaxf(-mud, 0.f);
    }
    // B * (P_Loads . mapL_s) duty
    float s2 = 0.f;
    for (int j = lane; j < 600; j += 64) s2 += PL[(size_t)b * 600 + j] * mls[j];
    s += 32768.0f * s2;
    for (int m = 32; m >= 1; m >>= 1) s += __shfl_xor(s, m);
    if (lane == 0) kkt_rows[b] = s;
    // |Volt[b,300]| global-scalar duty
    float v3 = (lane == 0) ? fabsf(Volt[(size_t)b * 600 + 300]) : 0.f;
    if (lane == 0) sred[w] = v3;
    __syncthreads();
    if (t == 0) atomicAdd(scalar_acc, sred[0] + sred[1] + sred[2] + sred[3]);
}

// ---------------- main fused GEMM + epilogues ----------------
__global__ __launch_bounds__(256, 4) void kkt_main(
    const float* __restrict__ Volt, const float* __restrict__ nolp,
    const float* __restrict__ PG,
    const float* __restrict__ mu_gu, const float* __restrict__ mu_gd,
    const float* __restrict__ mu_iu,
    const float* __restrict__ Gmax, const float* __restrict__ Gmin,
    const float* __restrict__ CPg,
    const unsigned short* __restrict__ Vbf, const unsigned short* __restrict__ BmF,
    const float* __restrict__ mapg_s, float* __restrict__ kkt_rows,
    float* __restrict__ scalar_acc, int useVbf) {

    // XCD-aware swizzle: a rowtile's 14 n-tile blocks share one XCD -> L2 reuse of A rows.
    int idx = blockIdx.x;
    int xcd = idx & 7;
    int q = idx >> 3;
    int nt = q % NTILES;
    int rg = q / NTILES;
    int rt = rg * 8 + xcd;
    int b0 = rt * 128;

    int t = threadIdx.x;
    int lane = t & 63, w = t >> 6, wr = w >> 1, wc = w & 1;

    __shared__ short8 Asm[1024];   // A tile, MFMA-fragment order
    __shared__ short8 Bsm[1024];   // B tile, MFMA-fragment order
    __shared__ float  redbuf[4];

    bool fastA = (nt < 12) && useVbf;
    const float* Af32 = (nt < 12) ? Volt : nolp;

    // per-thread slot geometry for the 4 staging instructions
    int rcA[4], kbA[4];
#pragma unroll
    for (int m = 0; m < 4; ++m) {
        int S = m * 256 + t;
        int ig = S >> 7, ks = (S >> 6) & 1, ln = S & 63;
        rcA[m] = ig * 16 + (ln & 15);
        kbA[m] = ks * 32 + ((ln >> 4) << 3);
    }

    f32x4 acc[4][4] = {};

    for (int kc = 0; kc < 10; ++kc) {
        int k0 = kc * 64;
        __syncthreads();
        const unsigned short* bSrc = BmF + (size_t)(nt * 10 + kc) * 1024 * 8;
#pragma unroll
        for (int m = 0; m < 4; ++m) {
            int S = m * 256 + t;
            __builtin_amdgcn_global_load_lds(
                (const __attribute__((address_space(1))) unsigned int*)(bSrc + (size_t)S * 8),
                (__attribute__((address_space(3))) unsigned int*)&Bsm[S], 16, 0, 0);
        }
        if (fastA) {
#pragma unroll
            for (int m = 0; m < 4; ++m) {
                int S = m * 256 + t;
                __builtin_amdgcn_global_load_lds(
                    (const __attribute__((address_space(1))) unsigned int*)(Vbf + (size_t)(b0 + rcA[m]) * 640 + k0 + kbA[m]),
                    (__attribute__((address_space(3))) unsigned int*)&Asm[S], 16, 0, 0);
            }
        } else {
#pragma unroll
            for (int m = 0; m < 4; ++m) {
                int S = m * 256 + t;
                int gk = k0 + kbA[m];
                short8 av = (short8)0;
                if (gk < 600) {   // chunks are 8-aligned and 600%8==0, so no partial chunk
                    const f32x4* p = (const f32x4*)(Af32 + (size_t)(b0 + rcA[m]) * 600 + gk);
                    f32x4 x0 = p[0], x1 = p[1];
                    uint2 a0, a1;
                    a0.x = pk2bf(x0[0], x0[1]); a0.y = pk2bf(x0[2], x0[3]);
                    a1.x = pk2bf(x1[0], x1[1]); a1.y = pk2bf(x1[2], x1[3]);
                    av = __builtin_bit_cast(short8, make_uint4(a0.x, a0.y, a1.x, a1.y));
                }
                Asm[S] = av;
            }
        }
        __syncthreads();
#pragma unroll
        for (int ks = 0; ks < 2; ++ks) {
            short8 af[4], bfr[4];
#pragma unroll
            for (int ii = 0; ii < 4; ++ii) af[ii] = Asm[((wr * 4 + ii) * 2 + ks) * 64 + lane];
#pragma unroll
            for (int jj = 0; jj < 4; ++jj) bfr[jj] = Bsm[((wc * 4 + jj) * 2 + ks) * 64 + lane];
#pragma unroll
            for (int ii = 0; ii < 4; ++ii)
#pragma unroll
                for (int jj = 0; jj < 4; ++jj)
                    acc[ii][jj] = __builtin_amdgcn_mfma_f32_16x16x32_bf16(af[ii], bfr[jj], acc[ii][jj], 0, 0, 0);
        }
    }

    // ---- section epilogues ----
    // C/D layout (m89): col = lane&15, row = (lane>>4)*4 + reg
    if (nt < 5) {
        // quad: global scalar += sum u*v  (v read fp32 for accuracy)
        float qa = 0.f;
#pragma unroll
        for (int ii = 0; ii < 4; ++ii)
#pragma unroll
            for (int jj = 0; jj < 4; ++jj)
#pragma unroll
                for (int r2 = 0; r2 < 4; ++r2) {
                    int row = wr * 64 + ii * 16 + ((lane >> 4) << 2) + r2;
                    int col = nt * 128 + wc * 64 + jj * 16 + (lane & 15);
                    if (col < 600) {
                        float v = Volt[(size_t)(b0 + row) * 600 + col];
                        qa += acc[ii][jj][r2] * v;
                    }
                }
        for (int m = 32; m >= 1; m >>= 1) qa += __shfl_xor(qa, m);
        if (lane == 0) redbuf[w] = qa;
        __syncthreads();
        if (t == 0) atomicAdd(scalar_acc, redbuf[0] + redbuf[1] + redbuf[2] + redbuf[3]);
    } else if (nt < 12) {
        // Ibr: i_up = re^2 + im^2 - 1 on interleaved column pairs
        float racc[16];
#pragma unroll
        for (int s = 0; s < 16; ++s) racc[s] = 0.f;
#pragma unroll
        for (int ii = 0; ii < 4; ++ii)
#pragma unroll
            for (int jj = 0; jj < 4; ++jj)
#pragma unroll
                for (int r2 = 0; r2 < 4; ++r2) {
                    float u = acc[ii][jj][r2];
                    float up = __shfl_xor(u, 1);
                    int col = nt * 128 + wc * 64 + jj * 16 + (lane & 15);
                    int l = (col - 640) >> 1;
                    float contrib = 0.f;
                    if (l < NLINE && !(lane & 1)) {
                        int row = wr * 64 + ii * 16 + ((lane >> 4) << 2) + r2;
                        float iu = u * u + up * up - 1.0f;
                        float mu = mu_iu[(size_t)(b0 + row) * NLINE + l];
                        contrib = fmaxf(iu, 0.f) + fabsf(mu * iu) + fmaxf(-mu, 0.f);
                    }
                    racc[ii * 4 + r2] += contrib;
                }
#pragma unroll
        for (int s = 0; s < 16; ++s) {
            float v = racc[s];
            v += __shfl_xor(v, 1); v += __shfl_xor(v, 2);
            v += __shfl_xor(v, 4); v += __shfl_xor(v, 8);
            if ((lane & 15) == 0) {
                int row = wr * 64 + (s >> 2) * 16 + ((lane >> 4) << 2) + (s & 3);
                atomicAdd(kkt_rows + b0 + row, v);
            }
        }
    } else {
        // stat + gen-limit terms + P_Gens part of mism
        float racc[16];
#pragma unroll
        for (int s = 0; s < 16; ++s) racc[s] = 0.f;
#pragma unroll
        for (int ii = 0; ii < 4; ++ii)
#pragma unroll
            for (int jj = 0; jj < 4; ++jj)
#pragma unroll
                for (int r2 = 0; r2 < 4; ++r2) {
                    int col = nt * 128 + wc * 64 + jj * 16 + (lane & 15);
                    int g = col - 1536;
                    float contrib = 0.f;
                    if (g < 138) {
                        int row = wr * 64 + ii * 16 + ((lane >> 4) << 2) + r2;
                        size_t ix = (size_t)(b0 + row) * 138 + g;
                        float u = acc[ii][jj][r2];
                        float gu = mu_gu[ix], gd = mu_gd[ix], pg = PG[ix];
                        float gmx = Gmax[g], gmn = Gmin[g];
                        float cst = (g < 69) ? CPg[g] : 0.f;
                        float t1 = pg - gmx, t2 = gmn - pg;
                        float st = u + gu - gd - cst;
                        contrib = fabsf(st) + fmaxf(t1, 0.f) + fmaxf(t2, 0.f)
                                + (fabsf(gu * t1) + fabsf(gd * t2)) * (1.0f / 69.0f)
                                + fmaxf(-gu, 0.f) + fmaxf(-gd, 0.f)
                                - 32768.0f * pg * mapg_s[g];
                    }
                    racc[ii * 4 + r2] += contrib;
                }
#pragma unroll
        for (int s = 0; s < 16; ++s) {
            float v = racc[s];
            v += __shfl_xor(v, 1); v += __shfl_xor(v, 2);
            v += __shfl_xor(v, 4); v += __shfl_xor(v, 8);
            if ((lane & 15) == 0) {
                int row = wr * 64 + (s >> 2) * 16 + ((lane >> 4) << 2) + (s & 3);
                atomicAdd(kkt_rows + b0 + row, v);
            }
        }
    }
}

// ---------------- finalize ----------------
__global__ void finalize_k(const float* __restrict__ kkt_rows, const float* __restrict__ scalar_acc,
                           float* __restrict__ out) {
    int i = blockIdx.x * 256 + threadIdx.x;
    out[i] = kkt_rows[i] + scalar_acc[0];
}

extern "C" void kernel_launch(void* const* d_in, const int* in_sizes, int n_in,
                              void* d_out, int out_size, void* d_ws, size_t ws_size,
                              hipStream_t stream) {
    const float* Volt  = (const float*)d_in[0];
    const float* PG    = (const float*)d_in[1];
    const float* PL    = (const float*)d_in[2];
    const float* nolp  = (const float*)d_in[3];
    const float* mu_gu = (const float*)d_in[4];
    const float* mu_gd = (const float*)d_in[5];
    const float* mu_vu = (const float*)d_in[6];
    const float* mu_vd = (const float*)d_in[7];
    const float* mu_iu = (const float*)d_in[8];
    const float* Y     = (const float*)d_in[9];
    const float* Yconj = (const float*)d_in[10];
    const float* Ybr   = (const float*)d_in[11];
    const float* IM    = (const float*)d_in[12];
    const float* Mapg  = (const float*)d_in[13];
    const float* MapL  = (const float*)d_in[14];
    const float* Gmax  = (const float*)d_in[15];
    const float* Gmin  = (const float*)d_in[16];
    const float* CPg   = (const float*)d_in[17];

    char* ws = (char*)d_ws;
    float* scalar_acc       = (float*)(ws + WS_SCALAR);
    float* kkt_rows         = (float*)(ws + WS_KROWS);
    float* mapLs            = (float*)(ws + WS_MAPL);
    float* mapgs            = (float*)(ws + WS_MAPG);
    float* Atmp             = (float*)(ws + WS_ATMP);
    unsigned short* BmF     = (unsigned short*)(ws + WS_BMF);
    unsigned short* Vbf     = (unsigned short*)(ws + WS_VBF);

    int useVbf = (ws_size >= (size_t)WS_NEED_FAST) ? 1 : 0;

    hipMemsetAsync(d_ws, 0, WS_ZERO_BYTES, stream);
    prep_colsums<<<185, 256, 0, stream>>>(MapL, Mapg, mapLs, mapgs);
    prep_A<<<520, 256, 0, stream>>>(Ybr, IM, Atmp);
    prep_packF<<<560, 256, 0, stream>>>(Y, Yconj, Mapg, Atmp, BmF);
    prep_duties_conv<<<8192, 256, 0, stream>>>(Volt, PL, mu_vu, mu_vd, mapLs,
                                               Vbf, kkt_rows, scalar_acc, useVbf);
    kkt_main<<<RTILES * NTILES, 256, 0, stream>>>(Volt, nolp, PG, mu_gu, mu_gd, mu_iu,
                                                  Gmax, Gmin, CPg, Vbf, BmF, mapgs,
                                                  kkt_rows, scalar_acc, useVbf);
    finalize_k<<<BATCH / 256, 256, 0, stream>>>(kkt_rows, scalar_acc, (float*)d_out);
}